// Round 2
// baseline (1017.084 us; speedup 1.0000x reference)
//
#include <hip/hip_runtime.h>
#include <hip/hip_bf16.h>
#include <stdint.h>

using bf16 = __hip_bfloat16;
typedef __attribute__((ext_vector_type(8))) short short8;
typedef __attribute__((ext_vector_type(4))) float f32x4;

#define LRELU_SLOPE 0.01f

// ---------------------------------------------------------------------------
// GEMM: C(N,Dout) = act(A(N,K) @ BT(Dout,K)^T + bias)
// A, BT, C are bf16; bias fp32; optional fp32 copy Cf (ld = ldcf).
// Block = 256 thr = 4 waves; block tile 64(M) x 128(N); each wave 32x64 via
// 2x4 grid of 16x16x32 MFMAs.
// MFMA layouts (measured, cdna_hip_programming.md §3):
//   A-frag: lane holds A[row0 + (lane&15)][k0 + (lane>>4)*8 + j], j=0..7
//   B-frag: lane holds B[k0 + (lane>>4)*8 + j][col0 + (lane&15)] = BT[col][k..]
//   C/D   : col = lane&15, row = (lane>>4)*4 + reg
// ---------------------------------------------------------------------------
__global__ __launch_bounds__(256) void gemm_bf16_kernel(
    const bf16* __restrict__ A, int lda,
    const bf16* __restrict__ BT,
    const float* __restrict__ bias,
    bf16* __restrict__ C, int ldc,
    float* __restrict__ Cf, int ldcf,
    int N, int K, int Dout, int act)
{
    const int wave = threadIdx.x >> 6;
    const int lane = threadIdx.x & 63;
    const int m16  = lane & 15;
    const int q    = lane >> 4;
    const int row0 = blockIdx.x * 64  + (wave & 1) * 32;
    const int col0 = blockIdx.y * 128 + (wave >> 1) * 64;

    f32x4 acc[2][4];
#pragma unroll
    for (int mi = 0; mi < 2; ++mi)
#pragma unroll
        for (int ni = 0; ni < 4; ++ni)
            acc[mi][ni] = (f32x4){0.f, 0.f, 0.f, 0.f};

    const short8 zero8 = {0, 0, 0, 0, 0, 0, 0, 0};
    for (int k0 = 0; k0 < K; k0 += 32) {
        short8 a[2], b[4];
#pragma unroll
        for (int mi = 0; mi < 2; ++mi) {
            int row = row0 + mi * 16 + m16;
            a[mi] = (row < N)
                ? *reinterpret_cast<const short8*>(A + (size_t)row * lda + k0 + q * 8)
                : zero8;
        }
#pragma unroll
        for (int ni = 0; ni < 4; ++ni) {
            int col = col0 + ni * 16 + m16;
            b[ni] = *reinterpret_cast<const short8*>(BT + (size_t)col * K + k0 + q * 8);
        }
#pragma unroll
        for (int mi = 0; mi < 2; ++mi)
#pragma unroll
            for (int ni = 0; ni < 4; ++ni)
                acc[mi][ni] = __builtin_amdgcn_mfma_f32_16x16x32_bf16(
                    a[mi], b[ni], acc[mi][ni], 0, 0, 0);
    }

#pragma unroll
    for (int mi = 0; mi < 2; ++mi) {
        int rbase = row0 + mi * 16 + q * 4;
#pragma unroll
        for (int ni = 0; ni < 4; ++ni) {
            int col = col0 + ni * 16 + m16;
            float bv = bias[col];
#pragma unroll
            for (int r = 0; r < 4; ++r) {
                int row = rbase + r;
                if (row < N) {
                    float v = acc[mi][ni][r] + bv;
                    if (act) v = (v > 0.f) ? v : LRELU_SLOPE * v;
                    C[(size_t)row * ldc + col] = __float2bfloat16(v);
                    if (Cf) Cf[(size_t)row * ldcf + col] = v;
                }
            }
        }
    }
}

// ---------------------------------------------------------------------------
// Conversion helpers
// ---------------------------------------------------------------------------
// W (K x Dout) fp32 row-major -> WT (Dout x K) bf16
__global__ void convT_kernel(const float* __restrict__ W, bf16* __restrict__ WT,
                             int K, int Dout)
{
    int t = blockIdx.x * 256 + threadIdx.x;
    if (t < K * Dout) {
        int k = t / Dout, n = t % Dout;
        WT[(size_t)n * K + k] = __float2bfloat16(W[t]);
    }
}

__global__ void cvt_kernel(const float* __restrict__ X, bf16* __restrict__ Y, int n)
{
    int t = blockIdx.x * 256 + threadIdx.x;
    if (t < n) Y[t] = __float2bfloat16(X[t]);
}

// ---------------------------------------------------------------------------
// CSR build
// ---------------------------------------------------------------------------
__global__ void hist_kernel(const int* __restrict__ col, int* __restrict__ cnt, int E)
{
    int e = blockIdx.x * 256 + threadIdx.x;
    if (e < E) atomicAdd(&cnt[col[e]], 1);
}

// phase 1: per-block (256-wide) exclusive scan; block totals to bsum
__global__ void blockscan_kernel(const int* __restrict__ cnt, int* __restrict__ off,
                                 int* __restrict__ bsum, int N)
{
    __shared__ int sm[256];
    int i = blockIdx.x * 256 + threadIdx.x;
    int v = (i < N) ? cnt[i] : 0;
    sm[threadIdx.x] = v;
    __syncthreads();
    for (int d = 1; d < 256; d <<= 1) {
        int t = (threadIdx.x >= (unsigned)d) ? sm[threadIdx.x - d] : 0;
        __syncthreads();
        sm[threadIdx.x] += t;
        __syncthreads();
    }
    if (i < N) off[i] = sm[threadIdx.x] - v;
    if (threadIdx.x == 255) bsum[blockIdx.x] = sm[255];
}

// phase 2: single-block exclusive scan of block sums (nb <= 512)
__global__ void bscan_kernel(int* __restrict__ bsum, int nb)
{
    __shared__ int sm[512];
    int v = (threadIdx.x < (unsigned)nb) ? bsum[threadIdx.x] : 0;
    sm[threadIdx.x] = v;
    __syncthreads();
    for (int d = 1; d < 512; d <<= 1) {
        int t = (threadIdx.x >= (unsigned)d) ? sm[threadIdx.x - d] : 0;
        __syncthreads();
        sm[threadIdx.x] += t;
        __syncthreads();
    }
    if (threadIdx.x < (unsigned)nb) bsum[threadIdx.x] = sm[threadIdx.x] - v;
}

// phase 3: add block offsets; set off[N] = E
__global__ void addoff_kernel(int* __restrict__ off, const int* __restrict__ bsum,
                              int N, int E)
{
    int i = blockIdx.x * 256 + threadIdx.x;
    if (i < N) off[i] += bsum[blockIdx.x];
    if (i == 0) off[N] = E;
}

__global__ void invcnt_kernel(const int* __restrict__ cnt, float* __restrict__ icnt, int N)
{
    int i = blockIdx.x * 256 + threadIdx.x;
    if (i < N) icnt[i] = 1.0f / fmaxf((float)cnt[i], 1.0f);
}

__global__ void fill_kernel(const int* __restrict__ row, const int* __restrict__ col,
                            const float* __restrict__ ea, const int* __restrict__ off,
                            int* __restrict__ fil, int* __restrict__ row_s,
                            float* __restrict__ ea_s, int E)
{
    int e = blockIdx.x * 256 + threadIdx.x;
    if (e < E) {
        int c = col[e];
        int p = atomicAdd(&fil[c], 1);
        int pos = off[c] + p;
        row_s[pos] = row[e];
        ea_s[pos]  = ea[e];
    }
}

// ---------------------------------------------------------------------------
// one wave per node; lane handles channels 2*lane, 2*lane+1 of D=128
// ---------------------------------------------------------------------------
__global__ void agg_kernel(const int* __restrict__ off,
                           const int* __restrict__ row_s,
                           const float* __restrict__ ea_s,
                           const bf16* __restrict__ s,
                           const float* __restrict__ icnt,
                           bf16* __restrict__ cat, int N)
{
    int wid  = (int)((blockIdx.x * blockDim.x + threadIdx.x) >> 6);
    int lane = threadIdx.x & 63;
    if (wid >= N) return;
    int b = off[wid], e = off[wid + 1];
    float ax = 0.f, ay = 0.f;
    for (int i = b; i < e; ++i) {
        int r   = row_s[i];
        float w = ea_s[i];
        uint32_t u = *reinterpret_cast<const uint32_t*>(s + (size_t)r * 128 + 2 * lane);
        union { uint32_t u; float f; } lo, hi;
        lo.u = u << 16;
        hi.u = u & 0xffff0000u;
        ax += w * lo.f;
        ay += w * hi.f;
    }
    float ic = icnt[wid];
    cat[(size_t)wid * 256 + 2 * lane]     = __float2bfloat16(ax * ic);
    cat[(size_t)wid * 256 + 2 * lane + 1] = __float2bfloat16(ay * ic);
}

// ---------------------------------------------------------------------------
// GRU elementwise: h' = (1-z)*n + z*h   (h carried fp32 in d_out)
// ---------------------------------------------------------------------------
__global__ void gru_kernel(const bf16* __restrict__ gi,
                           const bf16* __restrict__ gh,
                           float* __restrict__ h,       // in/out, ld 128
                           bf16* __restrict__ hb,       // bf16 copy, ld 256
                           int N)
{
    int t = blockIdx.x * 256 + threadIdx.x;
    if (t >= N * 128) return;
    int v = t >> 7, c = t & 127;
    size_t base = (size_t)v * 384 + c;
    float ir  = __bfloat162float(gi[base]);
    float iz  = __bfloat162float(gi[base + 128]);
    float in_ = __bfloat162float(gi[base + 256]);
    float hr  = __bfloat162float(gh[base]);
    float hz  = __bfloat162float(gh[base + 128]);
    float hn  = __bfloat162float(gh[base + 256]);
    float hv  = h[t];
    float r = 1.f / (1.f + __expf(-(ir + hr)));
    float z = 1.f / (1.f + __expf(-(iz + hz)));
    float n = tanhf(in_ + r * hn);
    float hnew = (1.f - z) * n + z * hv;
    h[t] = hnew;
    hb[(size_t)v * 256 + c] = __float2bfloat16(hnew);
}

// ---------------------------------------------------------------------------
extern "C" void kernel_launch(void* const* d_in, const int* in_sizes, int n_in,
                              void* d_out, int out_size, void* d_ws, size_t ws_size,
                              hipStream_t stream)
{
    const float* x       = (const float*)d_in[0];
    const int*   ei      = (const int*)d_in[1];
    const float* ea      = (const float*)d_in[2];
    // d_in[3] = batch (unused)
    const float* W_embed = (const float*)d_in[4];
    const float* b_embed = (const float*)d_in[5];
    const float* W_snd   = (const float*)d_in[6];
    const float* b_snd   = (const float*)d_in[7];
    const float* W_rec   = (const float*)d_in[8];
    const float* b_rec   = (const float*)d_in[9];
    const float* W_ih    = (const float*)d_in[10];
    const float* b_ih    = (const float*)d_in[11];
    const float* W_hh    = (const float*)d_in[12];
    const float* b_hh    = (const float*)d_in[13];

    const int N = in_sizes[3];   // batch has N elements
    const int E = in_sizes[2];   // edge_attr has E elements

    float* hout = (float*)d_out; // fp32 h carry lives in d_out (ld 128)

    // ---- workspace carve (~116 MB) ----
    char* p = (char*)d_ws;
    auto carve = [&](size_t bytes) {
        char* r = p;
        p += (bytes + 255) & ~(size_t)255;
        return (void*)r;
    };
    bf16*  xb    = (bf16*) carve((size_t)N * 64 * 2);
    bf16*  cat   = (bf16*) carve((size_t)N * 256 * 2);  // [agg | h] bf16
    // sbuf and mbuf are carved back-to-back; ghbuf aliases their union
    // (sizes are exact multiples of 256B so the region is contiguous).
    bf16*  sbuf  = (bf16*) carve((size_t)N * 128 * 2);
    bf16*  mbuf  = (bf16*) carve((size_t)N * 256 * 2);
    bf16*  ghbuf = sbuf;                                // N*384 bf16 alias
    bf16*  gibuf = (bf16*) carve((size_t)N * 384 * 2);
    int*   cnt   = (int*)  carve((size_t)N * 4);
    int*   fil   = (int*)  carve((size_t)N * 4);
    int*   off   = (int*)  carve((size_t)(N + 1) * 4);
    int*   bsum  = (int*)  carve((size_t)512 * 4);
    float* icnt  = (float*)carve((size_t)N * 4);
    int*   row_s = (int*)  carve((size_t)E * 4);
    float* ea_s  = (float*)carve((size_t)E * 4);
    bf16*  wtE   = (bf16*) carve((size_t)128 * 64 * 2);
    bf16*  wtS   = (bf16*) carve((size_t)128 * 128 * 2);
    bf16*  wtR   = (bf16*) carve((size_t)256 * 256 * 2);
    bf16*  wtI   = (bf16*) carve((size_t)384 * 256 * 2);
    bf16*  wtH   = (bf16*) carve((size_t)384 * 128 * 2);

    const int* rowp = ei;
    const int* colp = ei + E;

    hipMemsetAsync(cnt, 0, (size_t)N * 4, stream);
    hipMemsetAsync(fil, 0, (size_t)N * 4, stream);

    const int TB = 256;
    auto nb = [](int n) { return (n + 255) / 256; };

    // input conversions (fp32 -> bf16), weight convert+transpose
    cvt_kernel<<<nb(N * 64), TB, 0, stream>>>(x, xb, N * 64);
    convT_kernel<<<nb(64 * 128),  TB, 0, stream>>>(W_embed, wtE, 64, 128);
    convT_kernel<<<nb(128 * 128), TB, 0, stream>>>(W_snd,   wtS, 128, 128);
    convT_kernel<<<nb(256 * 256), TB, 0, stream>>>(W_rec,   wtR, 256, 256);
    convT_kernel<<<nb(256 * 384), TB, 0, stream>>>(W_ih,    wtI, 256, 384);
    convT_kernel<<<nb(128 * 384), TB, 0, stream>>>(W_hh,    wtH, 128, 384);

    // CSR build
    hist_kernel<<<nb(E), TB, 0, stream>>>(colp, cnt, E);
    blockscan_kernel<<<nb(N), TB, 0, stream>>>(cnt, off, bsum, N);
    bscan_kernel<<<1, 512, 0, stream>>>(bsum, nb(N));
    addoff_kernel<<<nb(N), TB, 0, stream>>>(off, bsum, N, E);
    invcnt_kernel<<<nb(N), TB, 0, stream>>>(cnt, icnt, N);
    fill_kernel<<<nb(E), TB, 0, stream>>>(rowp, colp, ea, off, fil, row_s, ea_s, E);

    auto gemm = [&](const bf16* Ap, int lda, const bf16* BTp, const float* bp,
                    bf16* Cp, int ldc, float* Cfp, int ldcf,
                    int K, int Dout, int act) {
        dim3 g((N + 63) / 64, Dout / 128);
        gemm_bf16_kernel<<<g, TB, 0, stream>>>(Ap, lda, BTp, bp, Cp, ldc, Cfp, ldcf,
                                               N, K, Dout, act);
    };

    // embed: h = x @ W_embed + b  -> hout (fp32, d_out) + cat[:,128:256] (bf16)
    gemm(xb, 64, wtE, b_embed, cat + 128, 256, hout, 128, 64, 128, 0);

    for (int L = 0; L < 3; ++L) {
        // s = lrelu(h @ W_snd + b_snd)
        gemm(cat + 128, 256, wtS, b_snd, sbuf, 128, nullptr, 0, 128, 128, 1);
        // agg = segment_mean(s[row] * ea) -> cat[:,0:128]
        agg_kernel<<<(N * 64 + TB - 1) / TB, TB, 0, stream>>>(off, row_s, ea_s,
                                                              sbuf, icnt, cat, N);
        // m = lrelu([agg,h] @ W_rec + b_rec)
        gemm(cat, 256, wtR, b_rec, mbuf, 256, nullptr, 0, 256, 256, 1);
        // gi = m @ W_ih + b_ih
        gemm(mbuf, 256, wtI, b_ih, gibuf, 384, nullptr, 0, 256, 384, 0);
        // gh = h @ W_hh + b_hh   (ghbuf aliases sbuf+mbuf, both dead by now)
        gemm(cat + 128, 256, wtH, b_hh, ghbuf, 384, nullptr, 0, 128, 384, 0);
        // GRU update: h (fp32, d_out) and bf16 copy in cat[:,128:256]
        gru_kernel<<<nb(N * 128), TB, 0, stream>>>(gibuf, ghbuf, hout, cat + 128, N);
    }
}

// Round 3
// 699.022 us; speedup vs baseline: 1.4550x; 1.4550x over previous
//
#include <hip/hip_runtime.h>
#include <hip/hip_bf16.h>
#include <stdint.h>

using bf16 = __hip_bfloat16;
typedef __attribute__((ext_vector_type(8))) short short8;
typedef __attribute__((ext_vector_type(4))) float f32x4;

#define LRELU_SLOPE 0.01f

// async global->LDS, 16B per lane; LDS side is wave-uniform base + lane*16
#define GLOAD_LDS16(g, l) __builtin_amdgcn_global_load_lds( \
    (const __attribute__((address_space(1))) void*)(g),     \
    (__attribute__((address_space(3))) void*)(l), 16, 0, 0)

// ---------------------------------------------------------------------------
// LDS-staged GEMM (m97 structure): C(N,Dout) = act(A(N,K) @ BT(Dout,K)^T + b)
// Block 256 thr = 4 waves; tile 128(M) x 128(N); BK=32.
// LDS: As[128x32], Bs[128x32] bf16, pitch 64 B (lane-ordered, no padding —
// required by global_load_lds). Wave tile 64x64 = 4x4 MFMAs of 16x16x32.
// MFMA layouts (measured):
//   A-frag: lane holds A[row0+(lane&15)][k0+(lane>>4)*8+j], j=0..7
//   B-frag: lane holds BT[col0+(lane&15)][k0+(lane>>4)*8+j]
//   C/D   : col = lane&15, row = (lane>>4)*4 + reg
// ---------------------------------------------------------------------------
__global__ __launch_bounds__(256) void gemm_tile_kernel(
    const bf16* __restrict__ A, int lda,
    const bf16* __restrict__ BT,
    const float* __restrict__ bias,
    bf16* __restrict__ C, int ldc,
    float* __restrict__ Cf, int ldcf,
    int N, int K, int act)
{
    __shared__ bf16 smem[8192];          // As[0:4096] | Bs[4096:8192]
    bf16* As = smem;
    bf16* Bs = smem + 4096;

    const int t    = threadIdx.x;
    const int wv   = t >> 6;
    const int ln   = t & 63;
    const int m16  = ln & 15;
    const int q    = ln >> 4;
    const int row0 = blockIdx.x * 128;
    const int col0 = blockIdx.y * 128;
    const int wr   = (wv & 1) * 64;      // wave row base within tile
    const int wc   = (wv >> 1) * 64;     // wave col base within tile

    // staging assignment: thread t loads row (t>>2), 16B chunk (t&3)
    const int srow   = t >> 2;
    const int schunk = (t & 3) * 8;      // elem offset

    int ra0 = row0 + srow;       if (ra0 > N - 1) ra0 = N - 1;
    int ra1 = row0 + 64 + srow;  if (ra1 > N - 1) ra1 = N - 1;
    const bf16* gA0 = A  + (size_t)ra0 * lda + schunk;
    const bf16* gA1 = A  + (size_t)ra1 * lda + schunk;
    const bf16* gB0 = BT + (size_t)(col0 + srow)      * K + schunk;
    const bf16* gB1 = BT + (size_t)(col0 + 64 + srow) * K + schunk;

    f32x4 acc[4][4];
#pragma unroll
    for (int mi = 0; mi < 4; ++mi)
#pragma unroll
        for (int ni = 0; ni < 4; ++ni)
            acc[mi][ni] = (f32x4){0.f, 0.f, 0.f, 0.f};

    for (int k0 = 0; k0 < K; k0 += 32) {
        GLOAD_LDS16(gA0 + k0, As +        wv * 512);
        GLOAD_LDS16(gA1 + k0, As + 2048 + wv * 512);
        GLOAD_LDS16(gB0 + k0, Bs +        wv * 512);
        GLOAD_LDS16(gB1 + k0, Bs + 2048 + wv * 512);
        __syncthreads();

        short8 a[4], b[4];
#pragma unroll
        for (int mi = 0; mi < 4; ++mi)
            a[mi] = *reinterpret_cast<const short8*>(As + (wr + mi * 16 + m16) * 32 + q * 8);
#pragma unroll
        for (int ni = 0; ni < 4; ++ni)
            b[ni] = *reinterpret_cast<const short8*>(Bs + (wc + ni * 16 + m16) * 32 + q * 8);
#pragma unroll
        for (int mi = 0; mi < 4; ++mi)
#pragma unroll
            for (int ni = 0; ni < 4; ++ni)
                acc[mi][ni] = __builtin_amdgcn_mfma_f32_16x16x32_bf16(
                    a[mi], b[ni], acc[mi][ni], 0, 0, 0);
        __syncthreads();
    }

#pragma unroll
    for (int mi = 0; mi < 4; ++mi) {
        int rbase = row0 + wr + mi * 16 + q * 4;
#pragma unroll
        for (int ni = 0; ni < 4; ++ni) {
            int col = col0 + wc + ni * 16 + m16;
            float bv = bias[col];
#pragma unroll
            for (int r = 0; r < 4; ++r) {
                int row = rbase + r;
                if (row < N) {
                    float v = acc[mi][ni][r] + bv;
                    if (act) v = (v > 0.f) ? v : LRELU_SLOPE * v;
                    C[(size_t)row * ldc + col] = __float2bfloat16(v);
                    if (Cf) Cf[(size_t)row * ldcf + col] = v;
                }
            }
        }
    }
}

// ---------------------------------------------------------------------------
// prep: x fp32->bf16 + 5 weight convert/transpose (W KxDout fp32 -> DoutxK bf16)
// ---------------------------------------------------------------------------
__global__ void prep_kernel(const float* __restrict__ x, bf16* __restrict__ xb, int nx,
                            const float* __restrict__ W0, bf16* __restrict__ T0,
                            const float* __restrict__ W1, bf16* __restrict__ T1,
                            const float* __restrict__ W2, bf16* __restrict__ T2,
                            const float* __restrict__ W3, bf16* __restrict__ T3,
                            const float* __restrict__ W4, bf16* __restrict__ T4)
{
    int t = blockIdx.x * 256 + threadIdx.x;
    if (t < nx) { xb[t] = __float2bfloat16(x[t]); return; }
    t -= nx;
    if (t < 8192)  { T0[(size_t)(t % 128) * 64  + t / 128] = __float2bfloat16(W0[t]); return; }
    t -= 8192;
    if (t < 16384) { T1[(size_t)(t % 128) * 128 + t / 128] = __float2bfloat16(W1[t]); return; }
    t -= 16384;
    if (t < 65536) { T2[(size_t)(t % 256) * 256 + t / 256] = __float2bfloat16(W2[t]); return; }
    t -= 65536;
    if (t < 98304) { T3[(size_t)(t % 384) * 256 + t / 384] = __float2bfloat16(W3[t]); return; }
    t -= 98304;
    if (t < 49152) { T4[(size_t)(t % 384) * 128 + t / 384] = __float2bfloat16(W4[t]); return; }
}

// ---------------------------------------------------------------------------
// CSR build
// ---------------------------------------------------------------------------
__global__ void hist_kernel(const int* __restrict__ col, int* __restrict__ cnt, int E)
{
    int e = blockIdx.x * 256 + threadIdx.x;
    if (e < E) atomicAdd(&cnt[col[e]], 1);
}

__global__ void blockscan_kernel(const int* __restrict__ cnt, int* __restrict__ off,
                                 int* __restrict__ bsum, int N)
{
    __shared__ int sm[256];
    int i = blockIdx.x * 256 + threadIdx.x;
    int v = (i < N) ? cnt[i] : 0;
    sm[threadIdx.x] = v;
    __syncthreads();
    for (int d = 1; d < 256; d <<= 1) {
        int tv = (threadIdx.x >= (unsigned)d) ? sm[threadIdx.x - d] : 0;
        __syncthreads();
        sm[threadIdx.x] += tv;
        __syncthreads();
    }
    if (i < N) off[i] = sm[threadIdx.x] - v;
    if (threadIdx.x == 255) bsum[blockIdx.x] = sm[255];
}

__global__ void bscan_kernel(int* __restrict__ bsum, int nb)
{
    __shared__ int sm[512];
    int v = (threadIdx.x < (unsigned)nb) ? bsum[threadIdx.x] : 0;
    sm[threadIdx.x] = v;
    __syncthreads();
    for (int d = 1; d < 512; d <<= 1) {
        int tv = (threadIdx.x >= (unsigned)d) ? sm[threadIdx.x - d] : 0;
        __syncthreads();
        sm[threadIdx.x] += tv;
        __syncthreads();
    }
    if (threadIdx.x < (unsigned)nb) bsum[threadIdx.x] = sm[threadIdx.x] - v;
}

// add block offsets; off[N]=E; icnt = 1/max(cnt,1)
__global__ void addoff_kernel(int* __restrict__ off, const int* __restrict__ bsum,
                              const int* __restrict__ cnt, float* __restrict__ icnt,
                              int N, int E)
{
    int i = blockIdx.x * 256 + threadIdx.x;
    if (i < N) {
        off[i] += bsum[blockIdx.x];
        icnt[i] = 1.0f / fmaxf((float)cnt[i], 1.0f);
    }
    if (i == 0) off[N] = E;
}

__global__ void fill_kernel(const int* __restrict__ row, const int* __restrict__ col,
                            const float* __restrict__ ea, const int* __restrict__ off,
                            int* __restrict__ fil, int* __restrict__ row_s,
                            float* __restrict__ ea_s, int E)
{
    int e = blockIdx.x * 256 + threadIdx.x;
    if (e < E) {
        int c = col[e];
        int p = atomicAdd(&fil[c], 1);
        int pos = off[c] + p;
        row_s[pos] = row[e];
        ea_s[pos]  = ea[e];
    }
}

// ---------------------------------------------------------------------------
// aggregation: one wave per node; 4 x 16-lane groups, each group handles one
// edge per trip (16 lanes x 16B = whole 256B s-row). 4 edges in flight.
// Butterfly-reduce across groups, group-0 lanes store.
// ---------------------------------------------------------------------------
__global__ void agg_kernel(const int* __restrict__ off,
                           const int* __restrict__ row_s,
                           const float* __restrict__ ea_s,
                           const bf16* __restrict__ s,
                           const float* __restrict__ icnt,
                           bf16* __restrict__ cat, int N)
{
    int wid  = (int)((blockIdx.x * blockDim.x + threadIdx.x) >> 6);
    int lane = threadIdx.x & 63;
    if (wid >= N) return;
    const int rg = lane >> 4;        // edge slot 0..3
    const int cl = lane & 15;        // channel chunk: channels cl*8..cl*8+7
    int b = off[wid], e = off[wid + 1];

    float acc[8];
#pragma unroll
    for (int j = 0; j < 8; ++j) acc[j] = 0.f;

    for (int i = b + rg; i < e; i += 4) {
        int   r = row_s[i];
        float w = ea_s[i];
        short8 v = *reinterpret_cast<const short8*>(s + (size_t)r * 128 + cl * 8);
#pragma unroll
        for (int j = 0; j < 8; ++j) {
            union { uint32_t u; float f; } cv;
            cv.u = ((uint32_t)(uint16_t)v[j]) << 16;
            acc[j] += w * cv.f;
        }
    }
    // reduce across the 4 edge-slot groups (lanes l, l^16, l^32, l^48)
#pragma unroll
    for (int j = 0; j < 8; ++j) {
        acc[j] += __shfl_xor(acc[j], 16, 64);
        acc[j] += __shfl_xor(acc[j], 32, 64);
    }
    if (rg == 0) {
        float ic = icnt[wid];
        short8 o;
#pragma unroll
        for (int j = 0; j < 8; ++j) {
            bf16 hv = __float2bfloat16(acc[j] * ic);
            o[j] = *reinterpret_cast<short*>(&hv);
        }
        *reinterpret_cast<short8*>(cat + (size_t)wid * 256 + cl * 8) = o;
    }
}

// ---------------------------------------------------------------------------
// GRU elementwise, 8 channels/thread: h' = (1-z)*n + z*h  (h fp32 in d_out)
// ---------------------------------------------------------------------------
__global__ void gru_kernel(const bf16* __restrict__ gi,
                           const bf16* __restrict__ gh,
                           float* __restrict__ h,       // in/out, ld 128
                           bf16* __restrict__ hb,       // bf16 copy, ld 256
                           int N)
{
    int t = blockIdx.x * 256 + threadIdx.x;
    if (t >= N * 16) return;
    int v = t >> 4, c = (t & 15) * 8;
    const bf16* gp = gi + (size_t)v * 384 + c;
    const bf16* hp = gh + (size_t)v * 384 + c;
    short8 ir8 = *reinterpret_cast<const short8*>(gp);
    short8 iz8 = *reinterpret_cast<const short8*>(gp + 128);
    short8 in8 = *reinterpret_cast<const short8*>(gp + 256);
    short8 hr8 = *reinterpret_cast<const short8*>(hp);
    short8 hz8 = *reinterpret_cast<const short8*>(hp + 128);
    short8 hn8 = *reinterpret_cast<const short8*>(hp + 256);
    float* hv = h + (size_t)v * 128 + c;
    f32x4 h0 = *reinterpret_cast<f32x4*>(hv);
    f32x4 h1 = *reinterpret_cast<f32x4*>(hv + 4);

    auto b2f = [](short s) {
        union { uint32_t u; float f; } cv;
        cv.u = ((uint32_t)(uint16_t)s) << 16;
        return cv.f;
    };

    f32x4 o0, o1;
    short8 ob;
#pragma unroll
    for (int j = 0; j < 8; ++j) {
        float r  = 1.f / (1.f + __expf(-(b2f(ir8[j]) + b2f(hr8[j]))));
        float z  = 1.f / (1.f + __expf(-(b2f(iz8[j]) + b2f(hz8[j]))));
        float n  = tanhf(b2f(in8[j]) + r * b2f(hn8[j]));
        float hvj = (j < 4) ? h0[j] : h1[j - 4];
        float hn_ = (1.f - z) * n + z * hvj;
        if (j < 4) o0[j] = hn_; else o1[j - 4] = hn_;
        bf16 hbv = __float2bfloat16(hn_);
        ob[j] = *reinterpret_cast<short*>(&hbv);
    }
    *reinterpret_cast<f32x4*>(hv)     = o0;
    *reinterpret_cast<f32x4*>(hv + 4) = o1;
    *reinterpret_cast<short8*>(hb + (size_t)v * 256 + c) = ob;
}

// ---------------------------------------------------------------------------
extern "C" void kernel_launch(void* const* d_in, const int* in_sizes, int n_in,
                              void* d_out, int out_size, void* d_ws, size_t ws_size,
                              hipStream_t stream)
{
    const float* x       = (const float*)d_in[0];
    const int*   ei      = (const int*)d_in[1];
    const float* ea      = (const float*)d_in[2];
    const float* W_embed = (const float*)d_in[4];
    const float* b_embed = (const float*)d_in[5];
    const float* W_snd   = (const float*)d_in[6];
    const float* b_snd   = (const float*)d_in[7];
    const float* W_rec   = (const float*)d_in[8];
    const float* b_rec   = (const float*)d_in[9];
    const float* W_ih    = (const float*)d_in[10];
    const float* b_ih    = (const float*)d_in[11];
    const float* W_hh    = (const float*)d_in[12];
    const float* b_hh    = (const float*)d_in[13];

    const int N = in_sizes[3];
    const int E = in_sizes[2];

    float* hout = (float*)d_out;   // fp32 h carry (ld 128)

    char* p = (char*)d_ws;
    auto carve = [&](size_t bytes) {
        char* r = p;
        p += (bytes + 255) & ~(size_t)255;
        return (void*)r;
    };
    bf16*  xb    = (bf16*) carve((size_t)N * 64 * 2);
    bf16*  cat   = (bf16*) carve((size_t)N * 256 * 2);   // [agg | h] bf16
    bf16*  sbuf  = (bf16*) carve((size_t)N * 128 * 2);
    bf16*  mbuf  = (bf16*) carve((size_t)N * 256 * 2);
    bf16*  ghbuf = sbuf;                                 // N*384 alias (contiguous)
    bf16*  gibuf = (bf16*) carve((size_t)N * 384 * 2);
    int*   cnt   = (int*)  carve((size_t)N * 4);
    int*   fil   = (int*)  carve((size_t)N * 4);
    int*   off   = (int*)  carve((size_t)(N + 1) * 4);
    int*   bsum  = (int*)  carve((size_t)512 * 4);
    float* icnt  = (float*)carve((size_t)N * 4);
    int*   row_s = (int*)  carve((size_t)E * 4);
    float* ea_s  = (float*)carve((size_t)E * 4);
    bf16*  wtE   = (bf16*) carve((size_t)128 * 64 * 2);
    bf16*  wtS   = (bf16*) carve((size_t)128 * 128 * 2);
    bf16*  wtR   = (bf16*) carve((size_t)256 * 256 * 2);
    bf16*  wtI   = (bf16*) carve((size_t)384 * 256 * 2);
    bf16*  wtH   = (bf16*) carve((size_t)384 * 128 * 2);

    const int* rowp = ei;
    const int* colp = ei + E;

    hipMemsetAsync(cnt, 0, (size_t)N * 4, stream);
    hipMemsetAsync(fil, 0, (size_t)N * 4, stream);

    const int TB = 256;
    auto nb = [](int n) { return (n + 255) / 256; };

    // prep: x->bf16 + all weight transposes in one launch
    prep_kernel<<<nb(N * 64 + 237568), TB, 0, stream>>>(
        x, xb, N * 64,
        W_embed, wtE, W_snd, wtS, W_rec, wtR, W_ih, wtI, W_hh, wtH);

    // CSR build
    hist_kernel<<<nb(E), TB, 0, stream>>>(colp, cnt, E);
    blockscan_kernel<<<nb(N), TB, 0, stream>>>(cnt, off, bsum, N);
    bscan_kernel<<<1, 512, 0, stream>>>(bsum, nb(N));
    addoff_kernel<<<nb(N), TB, 0, stream>>>(off, bsum, cnt, icnt, N, E);
    fill_kernel<<<nb(E), TB, 0, stream>>>(rowp, colp, ea, off, fil, row_s, ea_s, E);

    auto gemm = [&](const bf16* Ap, int lda, const bf16* BTp, const float* bp,
                    bf16* Cp, int ldc, float* Cfp, int ldcf,
                    int K, int Dout, int act) {
        dim3 g((N + 127) / 128, Dout / 128);
        gemm_tile_kernel<<<g, TB, 0, stream>>>(Ap, lda, BTp, bp, Cp, ldc,
                                               Cfp, ldcf, N, K, act);
    };

    // embed: h = x @ W_embed + b -> hout fp32 + cat[:,128:256] bf16
    gemm(xb, 64, wtE, b_embed, cat + 128, 256, hout, 128, 64, 128, 0);

    for (int L = 0; L < 3; ++L) {
        // s = lrelu(h @ W_snd + b_snd)
        gemm(cat + 128, 256, wtS, b_snd, sbuf, 128, nullptr, 0, 128, 128, 1);
        // agg = segment_mean(s[row] * ea) -> cat[:,0:128]
        agg_kernel<<<(N * 64 + TB - 1) / TB, TB, 0, stream>>>(off, row_s, ea_s,
                                                              sbuf, icnt, cat, N);
        // m = lrelu([agg,h] @ W_rec + b_rec)
        gemm(cat, 256, wtR, b_rec, mbuf, 256, nullptr, 0, 256, 256, 1);
        // gi = m @ W_ih + b_ih
        gemm(mbuf, 256, wtI, b_ih, gibuf, 384, nullptr, 0, 256, 384, 0);
        // gh = h @ W_hh + b_hh  (ghbuf aliases sbuf+mbuf, both dead)
        gemm(cat + 128, 256, wtH, b_hh, ghbuf, 384, nullptr, 0, 128, 384, 0);
        // GRU update
        gru_kernel<<<nb(N * 16), TB, 0, stream>>>(gibuf, ghbuf, hout, cat + 128, N);
    }
}